// Round 1
// baseline (372.647 us; speedup 1.0000x reference)
//
#include <hip/hip_runtime.h>
#include <math.h>

#define T_TOKENS 16384
#define D_DIM    2048
#define NEXP     256
#define TOPK     8
#define NGROUPS  8
#define NLIM     4
#define BM       32
#define BK       16
#define NTHREADS 128

// LDS:
//  As[BK][BM+4]      : A tile (transposed, padded)           2.3 KB
//  Bs[BK][NEXP+4]    : B tile (transposed, padded)          16.6 KB
//  Sc[BM][NEXP+4]    : logits -> scores (padded)            33.3 KB
//  hist[NEXP]        : per-WG load histogram                 1.0 KB
// total ~53 KB -> 2 WGs/CU (grid is 512 = 2/CU anyway)

__global__ __launch_bounds__(NTHREADS) void gate_kernel(
    const float* __restrict__ x,
    const float* __restrict__ w,
    const float* __restrict__ bias,
    float* __restrict__ out_w,
    float* __restrict__ out_idx,
    float* __restrict__ out_load) {

  __shared__ float As[BK][BM + 4];
  __shared__ float Bs[BK][NEXP + 4];
  __shared__ float Sc[BM][NEXP + 4];
  __shared__ int   hist[NEXP];

  const int tid = threadIdx.x;
  const int row0 = blockIdx.x * BM;
  const int tx = tid & 31;   // expert block
  const int ty = tid >> 5;   // token block 0..3  (tokens ty*8 .. ty*8+7)

  for (int i = tid; i < NEXP; i += NTHREADS) hist[i] = 0;

  // thread computes 8 tokens x 8 experts.
  // expert columns: j<4 -> tx*4+j ; j>=4 -> 128 + tx*4 + (j-4)
  float acc[8][8];
  #pragma unroll
  for (int i = 0; i < 8; ++i)
    #pragma unroll
    for (int j = 0; j < 8; ++j) acc[i][j] = 0.f;

  for (int k0 = 0; k0 < D_DIM; k0 += BK) {
    // ---- stage A: 32 tokens x 16 k = 512 floats, 128 thr x float4
    {
      const int m  = tid >> 2;         // 0..31
      const int kk = (tid & 3) * 4;    // 0,4,8,12
      const float4 av = *reinterpret_cast<const float4*>(
          &x[(size_t)(row0 + m) * D_DIM + k0 + kk]);
      As[kk + 0][m] = av.x; As[kk + 1][m] = av.y;
      As[kk + 2][m] = av.z; As[kk + 3][m] = av.w;
    }
    // ---- stage B: 256 experts x 16 k = 1024 float4, 128 thr x 8
    #pragma unroll
    for (int i = 0; i < 8; ++i) {
      const int f  = tid + i * NTHREADS;  // 0..1023
      const int e  = f >> 2;
      const int kk = (f & 3) * 4;
      const float4 bv = *reinterpret_cast<const float4*>(
          &w[(size_t)e * D_DIM + k0 + kk]);
      Bs[kk + 0][e] = bv.x; Bs[kk + 1][e] = bv.y;
      Bs[kk + 2][e] = bv.z; Bs[kk + 3][e] = bv.w;
    }
    __syncthreads();

    #pragma unroll
    for (int kk = 0; kk < BK; ++kk) {
      float a[8], b[8];
      *reinterpret_cast<float4*>(&a[0]) =
          *reinterpret_cast<const float4*>(&As[kk][ty * 8]);
      *reinterpret_cast<float4*>(&a[4]) =
          *reinterpret_cast<const float4*>(&As[kk][ty * 8 + 4]);
      // contiguous 128-wide slabs -> conflict-free ds_read_b128
      *reinterpret_cast<float4*>(&b[0]) =
          *reinterpret_cast<const float4*>(&Bs[kk][tx * 4]);
      *reinterpret_cast<float4*>(&b[4]) =
          *reinterpret_cast<const float4*>(&Bs[kk][128 + tx * 4]);
      #pragma unroll
      for (int i = 0; i < 8; ++i)
        #pragma unroll
        for (int j = 0; j < 8; ++j)
          acc[i][j] = fmaf(a[i], b[j], acc[i][j]);
    }
    __syncthreads();
  }

  // ---- write logits to Sc
  #pragma unroll
  for (int i = 0; i < 8; ++i) {
    float4 lo = make_float4(acc[i][0], acc[i][1], acc[i][2], acc[i][3]);
    float4 hi = make_float4(acc[i][4], acc[i][5], acc[i][6], acc[i][7]);
    *reinterpret_cast<float4*>(&Sc[ty * 8 + i][tx * 4])       = lo;
    *reinterpret_cast<float4*>(&Sc[ty * 8 + i][128 + tx * 4]) = hi;
  }
  __syncthreads();

  // ---- routing: one wave per token, lane holds experts 4l..4l+3
  const int lane = tid & 63;
  const int wid  = tid >> 6;  // 0..1
  const float4 bsl = *reinterpret_cast<const float4*>(&bias[lane * 4]);
  const int g = lane >> 3;    // group of this lane's experts

  for (int m = wid; m < BM; m += 2) {
    float v[4];
    *reinterpret_cast<float4*>(v) =
        *reinterpret_cast<const float4*>(&Sc[m][lane * 4]);

    // softmax (match jax: subtract row max, exp, divide by sum)
    float mx = fmaxf(fmaxf(v[0], v[1]), fmaxf(v[2], v[3]));
    #pragma unroll
    for (int s = 1; s < 64; s <<= 1) mx = fmaxf(mx, __shfl_xor(mx, s));
    float ex[4], sum = 0.f;
    #pragma unroll
    for (int j = 0; j < 4; ++j) { ex[j] = expf(v[j] - mx); sum += ex[j]; }
    #pragma unroll
    for (int s = 1; s < 64; s <<= 1) sum += __shfl_xor(sum, s);
    float sc[4], sel[4];
    sc[0] = ex[0] / sum; sc[1] = ex[1] / sum;
    sc[2] = ex[2] / sum; sc[3] = ex[3] / sum;
    sel[0] = sc[0] + bsl.x; sel[1] = sc[1] + bsl.y;
    sel[2] = sc[2] + bsl.z; sel[3] = sc[3] + bsl.w;

    // keep original scores for the gather
    *reinterpret_cast<float4*>(&Sc[m][lane * 4]) =
        make_float4(sc[0], sc[1], sc[2], sc[3]);

    // group max (groups of 32 experts = 8 lanes)
    float gv = fmaxf(fmaxf(sel[0], sel[1]), fmaxf(sel[2], sel[3]));
    gv = fmaxf(gv, __shfl_xor(gv, 1));
    gv = fmaxf(gv, __shfl_xor(gv, 2));
    gv = fmaxf(gv, __shfl_xor(gv, 4));

    // top-4 groups, tie -> lower group index (jax.lax.top_k stability)
    unsigned gmask = 0;
    float gcur = gv;
    #pragma unroll
    for (int it = 0; it < NLIM; ++it) {
      float bv = gcur; int bi = g;
      #pragma unroll
      for (int s = 1; s < 64; s <<= 1) {
        float ov = __shfl_xor(bv, s);
        int   oi = __shfl_xor(bi, s);
        if (ov > bv || (ov == bv && oi < bi)) { bv = ov; bi = oi; }
      }
      gmask |= 1u << bi;
      if (g == bi) gcur = -INFINITY;
    }
    if (!((gmask >> g) & 1u)) {
      sel[0] = sel[1] = sel[2] = sel[3] = -INFINITY;
    }

    // top-8 experts, tie -> lower expert index
    const int gtok = row0 + m;
    #pragma unroll
    for (int it = 0; it < TOPK; ++it) {
      float bv = sel[0]; int bi = lane * 4;
      #pragma unroll
      for (int j = 1; j < 4; ++j)
        if (sel[j] > bv) { bv = sel[j]; bi = lane * 4 + j; }
      #pragma unroll
      for (int s = 1; s < 64; s <<= 1) {
        float ov = __shfl_xor(bv, s);
        int   oi = __shfl_xor(bi, s);
        if (ov > bv || (ov == bv && oi < bi)) { bv = ov; bi = oi; }
      }
      if (lane == 0) {
        out_w[(size_t)gtok * TOPK + it]   = Sc[m][bi] * 2.5f;
        out_idx[(size_t)gtok * TOPK + it] = (float)bi;
        atomicAdd(&hist[bi], 1);
      }
      if ((bi >> 2) == lane) sel[bi & 3] = -INFINITY;
    }
  }

  __syncthreads();
  for (int b = tid; b < NEXP; b += NTHREADS)
    if (hist[b]) atomicAdd(&out_load[b], (float)hist[b]);
}

extern "C" void kernel_launch(void* const* d_in, const int* in_sizes, int n_in,
                              void* d_out, int out_size, void* d_ws, size_t ws_size,
                              hipStream_t stream) {
  const float* x    = (const float*)d_in[0];
  const float* w    = (const float*)d_in[1];
  const float* bias = (const float*)d_in[2];
  float* out_w    = (float*)d_out;
  float* out_idx  = out_w + (size_t)T_TOKENS * TOPK;
  float* out_load = out_idx + (size_t)T_TOKENS * TOPK;

  hipMemsetAsync(out_load, 0, NEXP * sizeof(float), stream);
  gate_kernel<<<T_TOKENS / BM, NTHREADS, 0, stream>>>(
      x, w, bias, out_w, out_idx, out_load);
}